// Round 5
// baseline (35.160 us; speedup 1.0000x reference)
//
#include <hip/hip_runtime.h>
#include <math.h>

#define EPS_F 1e-10f

typedef __attribute__((ext_vector_type(4))) float f4;
typedef __attribute__((ext_vector_type(4))) unsigned int u4;
typedef __attribute__((ext_vector_type(2))) float f2;

typedef const __attribute__((address_space(1))) float4* gv4p;
typedef __attribute__((address_space(3))) float4* lv4p;

__device__ __forceinline__ f4 v_fabs(f4 x) {
  u4 u = __builtin_bit_cast(u4, x);
  u &= 0x7fffffffu;
  return __builtin_bit_cast(f4, u);
}
__device__ __forceinline__ f4 v_max(f4 a, f4 b) { return __builtin_elementwise_max(a, b); }
__device__ __forceinline__ f4 v_min(f4 a, f4 b) { return __builtin_elementwise_min(a, b); }
__device__ __forceinline__ f4 v_log(f4 x) {
  f4 r; r.x = __logf(x.x); r.y = __logf(x.y); r.z = __logf(x.z); r.w = __logf(x.w); return r;
}
__device__ __forceinline__ f4 v_rcp(f4 x) {
  f4 r;
  r.x = __builtin_amdgcn_rcpf(x.x); r.y = __builtin_amdgcn_rcpf(x.y);
  r.z = __builtin_amdgcn_rcpf(x.z); r.w = __builtin_amdgcn_rcpf(x.w);
  return r;
}
__device__ __forceinline__ f4 v_sqrt(f4 x) {
  f4 r;
  r.x = __builtin_amdgcn_sqrtf(x.x); r.y = __builtin_amdgcn_sqrtf(x.y);
  r.z = __builtin_amdgcn_sqrtf(x.z); r.w = __builtin_amdgcn_sqrtf(x.w);
  return r;
}
__device__ __forceinline__ f4 v_cos(f4 x) {
  f4 r; r.x = __cosf(x.x); r.y = __cosf(x.y); r.z = __cosf(x.z); r.w = __cosf(x.w); return r;
}

// sanitize: non-finite -> EPS, else abs (matches nan_to_num(nan/inf->eps) + abs)
__device__ __forceinline__ f4 v_san(f4 v) {
  f4 a = v_fabs(v);
  f4 r;
  r.x = (a.x <= __FLT_MAX__) ? a.x : EPS_F;
  r.y = (a.y <= __FLT_MAX__) ? a.y : EPS_F;
  r.z = (a.z <= __FLT_MAX__) ? a.z : EPS_F;
  r.w = (a.w <= __FLT_MAX__) ? a.w : EPS_F;
  return r;
}

// acos via minimax poly (|err| ~ 2e-8 rad)
__device__ __forceinline__ f4 v_acos(f4 r) {
  const f4 t = v_fabs(r);
  const f4 s = v_sqrt(1.0f - t);
  f4 p = f4{-0.0012624911f, -0.0012624911f, -0.0012624911f, -0.0012624911f};
  p = p * t +  0.0066700901f;
  p = p * t + -0.0170881256f;
  p = p * t +  0.0308918810f;
  p = p * t + -0.0501743046f;
  p = p * t +  0.0889789874f;
  p = p * t + -0.2145988016f;
  p = p * t +  1.5707963050f;
  const f4 ac = s * p;                         // acos(|r|)
  f4 res;
  res.x = (r.x < 0.0f) ? (3.14159265358979f - ac.x) : ac.x;
  res.y = (r.y < 0.0f) ? (3.14159265358979f - ac.y) : ac.y;
  res.z = (r.z < 0.0f) ? (3.14159265358979f - ac.z) : ac.z;
  res.w = (r.w < 0.0f) ? (3.14159265358979f - ac.w) : ac.w;
  return res;
}

// Fused ||logm - logm||_F^2 for TWO matrix pairs in lockstep:
// lanes = {D1_pairA, D2_pairA, D1_pairB, D2_pairB}. Returns {lossA, lossB}.
__device__ __forceinline__ f2 pair_loss(f4 a00, f4 a01, f4 a02,
                                        f4 a11, f4 a12, f4 a22) {
  const f4 q   = (a00 + a11 + a22) * (1.0f / 3.0f);
  const f4 b00 = a00 - q, b11 = a11 - q, b22 = a22 - q;
  const f4 p2  = b00 * b00 + b11 * b11 + b22 * b22 +
                 2.0f * (a01 * a01 + a02 * a02 + a12 * a12);

  // keep p away from 0 so downstream denominators (~p^2) stay normal
  f4 p = v_sqrt(p2 * (1.0f / 6.0f));
  p = v_max(p, 1e-5f * q + 1e-35f);

  const f4 pinv = v_rcp(p);
  const f4 detB = b00 * (b11 * b22 - a12 * a12)
                - a01 * (a01 * b22 - a12 * a02)
                + a02 * (a01 * a12 - b11 * a02);
  f4 r = detB * 0.5f * pinv * pinv * pinv;
  r = v_min(f4{1.0f, 1.0f, 1.0f, 1.0f}, v_max(f4{-1.0f, -1.0f, -1.0f, -1.0f}, r));
  const f4 phi  = v_acos(r) * (1.0f / 3.0f);
  const f4 twop = 2.0f * p;
  const f4 l1 = q + twop * v_cos(phi);                          // largest
  const f4 l3 = q + twop * v_cos(phi + 2.0943951023931953f);    // smallest
  const f4 l2 = 3.0f * q - l1 - l3;

  // A^2 (symmetric)
  const f4 s00 = a00 * a00 + a01 * a01 + a02 * a02;
  const f4 s01 = a00 * a01 + a01 * a11 + a02 * a12;
  const f4 s02 = a00 * a02 + a01 * a12 + a02 * a22;
  const f4 s11 = a01 * a01 + a11 * a11 + a12 * a12;
  const f4 s12 = a01 * a02 + a11 * a12 + a12 * a22;
  const f4 s22 = a02 * a02 + a12 * a12 + a22 * a22;

  // isolated extreme eigenvalue = alpha; beta = middle; gamma = other extreme
  const f4 g12 = l1 - l2, g23 = l2 - l3;
  f4 alpha, gamma;
  alpha.x = (g12.x >= g23.x) ? l1.x : l3.x;  gamma.x = (g12.x >= g23.x) ? l3.x : l1.x;
  alpha.y = (g12.y >= g23.y) ? l1.y : l3.y;  gamma.y = (g12.y >= g23.y) ? l3.y : l1.y;
  alpha.z = (g12.z >= g23.z) ? l1.z : l3.z;  gamma.z = (g12.z >= g23.z) ? l3.z : l1.z;
  alpha.w = (g12.w >= g23.w) ? l1.w : l3.w;  gamma.w = (g12.w >= g23.w) ? l3.w : l1.w;
  const f4 beta = l2;

  const f4 f_a = v_log(alpha + EPS_F) + EPS_F;
  const f4 f_b = v_log(beta  + EPS_F) + EPS_F;
  const f4 f_g = v_log(gamma + EPS_F) + EPS_F;

  // P_alpha = (A - beta I)(A - gamma I) / ((alpha-beta)(alpha-gamma))
  const f4 inv_den_a = v_rcp((alpha - beta) * (alpha - gamma));
  const f4 sbg = beta + gamma, pbg = beta * gamma;
  const f4 sab = alpha + beta, pab = alpha * beta;

  // divided difference of f over the close pair (beta,gamma), single rcp
  const f4 gap = gamma - beta;
  const f4 ga  = gamma - alpha;
  const f4 agap = v_fabs(gap);
  const f4 thr  = 1e-5f * v_max(v_fabs(beta), v_fabs(gamma));
  const f4 mid  = 0.5f * (beta + gamma) + EPS_F;
  f4 num, den;
  num.x = (agap.x > thr.x) ? (f_g.x - f_b.x) : 1.0f;
  den.x = (agap.x > thr.x) ? (gap.x * ga.x) : (mid.x * ga.x);
  num.y = (agap.y > thr.y) ? (f_g.y - f_b.y) : 1.0f;
  den.y = (agap.y > thr.y) ? (gap.y * ga.y) : (mid.y * ga.y);
  num.z = (agap.z > thr.z) ? (f_g.z - f_b.z) : 1.0f;
  den.z = (agap.z > thr.z) ? (gap.z * ga.z) : (mid.z * ga.z);
  num.w = (agap.w > thr.w) ? (f_g.w - f_b.w) : 1.0f;
  den.w = (agap.w > thr.w) ? (gap.w * ga.w) : (mid.w * ga.w);
  const f4 cg = num * v_rcp(den);

  const f4 wd = (f_a - f_b) * inv_den_a;

  // L_ij = f_b*[i==j] + wd*Pnum_ij + cg*N_ij
  const f4 L0 = f_b + wd * (s00 - sbg * a00 + pbg) + cg * (s00 - sab * a00 + pab);
  const f4 L1 =       wd * (s01 - sbg * a01)       + cg * (s01 - sab * a01);
  const f4 L2 =       wd * (s02 - sbg * a02)       + cg * (s02 - sab * a02);
  const f4 L3 = f_b + wd * (s11 - sbg * a11 + pbg) + cg * (s11 - sab * a11 + pab);
  const f4 L4 =       wd * (s12 - sbg * a12)       + cg * (s12 - sab * a12);
  const f4 L5 = f_b + wd * (s22 - sbg * a22 + pbg) + cg * (s22 - sab * a22 + pab);

  // pair A in lanes {x,y}, pair B in lanes {z,w}
  const float dA0 = L0.x - L0.y, dB0 = L0.z - L0.w;
  const float dA1 = L1.x - L1.y, dB1 = L1.z - L1.w;
  const float dA2 = L2.x - L2.y, dB2 = L2.z - L2.w;
  const float dA3 = L3.x - L3.y, dB3 = L3.z - L3.w;
  const float dA4 = L4.x - L4.y, dB4 = L4.z - L4.w;
  const float dA5 = L5.x - L5.y, dB5 = L5.z - L5.w;
  f2 out;
  out.x = dA0 * dA0 + dA3 * dA3 + dA5 * dA5 + 2.0f * (dA1 * dA1 + dA2 * dA2 + dA4 * dA4);
  out.y = dB0 * dB0 + dB3 * dB3 + dB5 * dB5 + 2.0f * (dB1 * dB1 + dB2 * dB2 + dB4 * dB4);
  return out;
}

#define CHUNK 512
#define CHUNK_FLOATS (CHUNK * 9)       // 4608 floats
#define CHUNK_V4 (CHUNK_FLOATS / 4)    // 1152 float4 per tensor

__global__ void __launch_bounds__(256, 4)
leloss_partial(const float* __restrict__ d1, const float* __restrict__ d2,
               float* __restrict__ partial, int nmat, int nchunk) {
  __shared__ float sA[CHUNK_FLOATS];
  __shared__ float sB[CHUNK_FLOATS];

  const int tid = threadIdx.x;
  float acc = 0.0f;

  for (int c = blockIdx.x; c < nchunk; c += gridDim.x) {
    const int base = c * CHUNK;            // first matrix of chunk
    const int rem  = nmat - base;          // matrices in this chunk (>=1)

    if (rem >= CHUNK) {
      // async global->LDS staging, width 16. idx = tid + k*256 keeps each
      // wave's destinations linear (wave-uniform base + lane*16); the partial
      // k=4 step activates whole waves only (idx<1152 <=> tid<128).
      const float4* g1 = reinterpret_cast<const float4*>(d1 + (size_t)base * 9);
      const float4* g2 = reinterpret_cast<const float4*>(d2 + (size_t)base * 9);
      float4* s4A = reinterpret_cast<float4*>(sA);
      float4* s4B = reinterpret_cast<float4*>(sB);
#pragma unroll
      for (int k = 0; k < 5; ++k) {
        const int idx = tid + k * 256;
        if (idx < CHUNK_V4) {
          __builtin_amdgcn_global_load_lds((gv4p)(g1 + idx), (lv4p)(s4A + idx), 16, 0, 0);
          __builtin_amdgcn_global_load_lds((gv4p)(g2 + idx), (lv4p)(s4B + idx), 16, 0, 0);
        }
      }
    } else {
      // tail chunk: scalar staging with bounds
      const int nflt = rem * 9;
      for (int k = tid; k < nflt; k += 256) {
        sA[k] = d1[(size_t)base * 9 + k];
        sB[k] = d2[(size_t)base * 9 + k];
      }
    }
    __syncthreads();

    {
      const int ia = min(tid, rem - 1);
      const int ib = min(tid + 256, rem - 1);
      const int oa = ia * 9, ob = ib * 9;   // stride-9 words, 9 coprime 32: conflict-free
      const f4 m00 = v_san(f4{sA[oa + 0], sB[oa + 0], sA[ob + 0], sB[ob + 0]});
      const f4 m01 = v_san(f4{sA[oa + 1], sB[oa + 1], sA[ob + 1], sB[ob + 1]});
      const f4 m02 = v_san(f4{sA[oa + 2], sB[oa + 2], sA[ob + 2], sB[ob + 2]});
      const f4 m11 = v_san(f4{sA[oa + 4], sB[oa + 4], sA[ob + 4], sB[ob + 4]});
      const f4 m12 = v_san(f4{sA[oa + 5], sB[oa + 5], sA[ob + 5], sB[ob + 5]});
      const f4 m22 = v_san(f4{sA[oa + 8], sB[oa + 8], sA[ob + 8], sB[ob + 8]});
      const f2 l = pair_loss(m00, m01, m02, m11, m12, m22);
      acc += (tid < rem ? l.x : 0.0f) + (tid + 256 < rem ? l.y : 0.0f);
    }
    __syncthreads();
  }

  // wave reduce (64 lanes)
#pragma unroll
  for (int off = 32; off > 0; off >>= 1) acc += __shfl_down(acc, off, 64);

  __shared__ float wsum[4];
  const int lane = tid & 63;
  const int wid  = tid >> 6;
  if (lane == 0) wsum[wid] = acc;
  __syncthreads();
  if (tid == 0) {
    partial[blockIdx.x] = wsum[0] + wsum[1] + wsum[2] + wsum[3];
  }
}

__global__ void __launch_bounds__(256)
leloss_reduce(const float* __restrict__ partial, int n,
              float* __restrict__ out, double inv_count) {
  double s = 0.0;
  for (int i = threadIdx.x; i < n; i += 256) s += (double)partial[i];
#pragma unroll
  for (int off = 32; off > 0; off >>= 1) s += __shfl_down(s, off, 64);

  __shared__ double wsum[4];
  const int lane = threadIdx.x & 63;
  const int wid  = threadIdx.x >> 6;
  if (lane == 0) wsum[wid] = s;
  __syncthreads();
  if (threadIdx.x == 0) {
    const double total = wsum[0] + wsum[1] + wsum[2] + wsum[3];
    out[0] = (float)(total * inv_count);
  }
}

extern "C" void kernel_launch(void* const* d_in, const int* in_sizes, int n_in,
                              void* d_out, int out_size, void* d_ws, size_t ws_size,
                              hipStream_t stream) {
  const float* d1 = (const float*)d_in[0];
  const float* d2 = (const float*)d_in[1];
  float* out = (float*)d_out;
  float* partial = (float*)d_ws;

  const long long nelem = (long long)in_sizes[0];
  const int nmat   = (int)(nelem / 9);
  const int nchunk = (nmat + CHUNK - 1) / CHUNK;
  const int nblocks = nchunk < 2048 ? nchunk : 2048;

  leloss_partial<<<nblocks, 256, 0, stream>>>(d1, d2, partial, nmat, nchunk);

  const double inv_count = 1.0 / ((double)nmat * 9.0);
  leloss_reduce<<<1, 256, 0, stream>>>(partial, nblocks, out, inv_count);
}

// Round 6
// 33.420 us; speedup vs baseline: 1.0521x; 1.0521x over previous
//
#include <hip/hip_runtime.h>
#include <math.h>

#define EPS_F 1e-10f

typedef __attribute__((ext_vector_type(4))) float f4;
typedef __attribute__((ext_vector_type(4))) unsigned int u4;
typedef __attribute__((ext_vector_type(2))) float f2;

__device__ __forceinline__ f4 v_fabs(f4 x) {
  u4 u = __builtin_bit_cast(u4, x);
  u &= 0x7fffffffu;
  return __builtin_bit_cast(f4, u);
}
__device__ __forceinline__ f4 v_max(f4 a, f4 b) { return __builtin_elementwise_max(a, b); }
__device__ __forceinline__ f4 v_min(f4 a, f4 b) { return __builtin_elementwise_min(a, b); }
__device__ __forceinline__ f4 v_log(f4 x) {
  f4 r; r.x = __logf(x.x); r.y = __logf(x.y); r.z = __logf(x.z); r.w = __logf(x.w); return r;
}
__device__ __forceinline__ f4 v_rcp(f4 x) {
  f4 r;
  r.x = __builtin_amdgcn_rcpf(x.x); r.y = __builtin_amdgcn_rcpf(x.y);
  r.z = __builtin_amdgcn_rcpf(x.z); r.w = __builtin_amdgcn_rcpf(x.w);
  return r;
}
__device__ __forceinline__ f4 v_sqrt(f4 x) {
  f4 r;
  r.x = __builtin_amdgcn_sqrtf(x.x); r.y = __builtin_amdgcn_sqrtf(x.y);
  r.z = __builtin_amdgcn_sqrtf(x.z); r.w = __builtin_amdgcn_sqrtf(x.w);
  return r;
}
__device__ __forceinline__ f4 v_cos(f4 x) {
  f4 r; r.x = __cosf(x.x); r.y = __cosf(x.y); r.z = __cosf(x.z); r.w = __cosf(x.w); return r;
}

// acos via minimax poly (|err| ~ 2e-8 rad)
__device__ __forceinline__ f4 v_acos(f4 r) {
  const f4 t = v_fabs(r);
  const f4 s = v_sqrt(1.0f - t);
  f4 p = f4{-0.0012624911f, -0.0012624911f, -0.0012624911f, -0.0012624911f};
  p = p * t +  0.0066700901f;
  p = p * t + -0.0170881256f;
  p = p * t +  0.0308918810f;
  p = p * t + -0.0501743046f;
  p = p * t +  0.0889789874f;
  p = p * t + -0.2145988016f;
  p = p * t +  1.5707963050f;
  const f4 ac = s * p;                         // acos(|r|)
  f4 res;
  res.x = (r.x < 0.0f) ? (3.14159265358979f - ac.x) : ac.x;
  res.y = (r.y < 0.0f) ? (3.14159265358979f - ac.y) : ac.y;
  res.z = (r.z < 0.0f) ? (3.14159265358979f - ac.z) : ac.z;
  res.w = (r.w < 0.0f) ? (3.14159265358979f - ac.w) : ac.w;
  return res;
}

// Fused ||logm(D1)-logm(D2)||_F^2 for TWO matrix pairs in lockstep:
// lanes = {D1_pairA, D2_pairA, D1_pairB, D2_pairB}. Returns {lossA, lossB}.
// Inputs: raw entries (abs applied inside; inputs assumed finite).
__device__ __forceinline__ f2 pair_loss(f4 a00, f4 a01, f4 a02,
                                        f4 a11, f4 a12, f4 a22) {
  a00 = v_fabs(a00); a01 = v_fabs(a01); a02 = v_fabs(a02);
  a11 = v_fabs(a11); a12 = v_fabs(a12); a22 = v_fabs(a22);

  const f4 q   = (a00 + a11 + a22) * (1.0f / 3.0f);
  const f4 b00 = a00 - q, b11 = a11 - q, b22 = a22 - q;
  const f4 p2  = b00 * b00 + b11 * b11 + b22 * b22 +
                 2.0f * (a01 * a01 + a02 * a02 + a12 * a12);

  // keep p away from 0 so downstream denominators (~p^2) stay normal
  f4 p = v_sqrt(p2 * (1.0f / 6.0f));
  p = v_max(p, 1e-5f * q + 1e-35f);

  const f4 pinv = v_rcp(p);
  const f4 detB = b00 * (b11 * b22 - a12 * a12)
                - a01 * (a01 * b22 - a12 * a02)
                + a02 * (a01 * a12 - b11 * a02);
  f4 r = detB * 0.5f * pinv * pinv * pinv;
  r = v_min(f4{1.0f, 1.0f, 1.0f, 1.0f}, v_max(f4{-1.0f, -1.0f, -1.0f, -1.0f}, r));
  const f4 phi  = v_acos(r) * (1.0f / 3.0f);
  const f4 twop = 2.0f * p;
  const f4 l1 = q + twop * v_cos(phi);                          // largest
  const f4 l3 = q + twop * v_cos(phi + 2.0943951023931953f);    // smallest
  const f4 l2 = 3.0f * q - l1 - l3;

  // A^2 (symmetric, unique entries)
  const f4 s00 = a00 * a00 + a01 * a01 + a02 * a02;
  const f4 s01 = a00 * a01 + a01 * a11 + a02 * a12;
  const f4 s02 = a00 * a02 + a01 * a12 + a02 * a22;
  const f4 s11 = a01 * a01 + a11 * a11 + a12 * a12;
  const f4 s12 = a01 * a02 + a11 * a12 + a12 * a22;
  const f4 s22 = a02 * a02 + a12 * a12 + a22 * a22;

  // isolated extreme eigenvalue = alpha; beta = middle; gamma = other extreme
  const f4 g12 = l1 - l2, g23 = l2 - l3;
  f4 alpha, gamma;
  alpha.x = (g12.x >= g23.x) ? l1.x : l3.x;  gamma.x = (g12.x >= g23.x) ? l3.x : l1.x;
  alpha.y = (g12.y >= g23.y) ? l1.y : l3.y;  gamma.y = (g12.y >= g23.y) ? l3.y : l1.y;
  alpha.z = (g12.z >= g23.z) ? l1.z : l3.z;  gamma.z = (g12.z >= g23.z) ? l3.z : l1.z;
  alpha.w = (g12.w >= g23.w) ? l1.w : l3.w;  gamma.w = (g12.w >= g23.w) ? l3.w : l1.w;
  const f4 beta = l2;

  // (outer +EPS on f cancels in all diffs; inner +EPS kept to match log(w+eps))
  const f4 f_a = v_log(alpha + EPS_F);
  const f4 f_b = v_log(beta  + EPS_F);
  const f4 f_g = v_log(gamma + EPS_F);

  const f4 inv_den_a = v_rcp((alpha - beta) * (alpha - gamma));

  // divided difference of f over the close pair (beta,gamma), single rcp
  const f4 gap = gamma - beta;
  const f4 ga  = gamma - alpha;
  const f4 agap = v_fabs(gap);
  const f4 thr  = 1e-5f * v_max(v_fabs(beta), v_fabs(gamma));
  const f4 mid  = 0.5f * (beta + gamma) + EPS_F;
  f4 num, den;
  num.x = (agap.x > thr.x) ? (f_g.x - f_b.x) : 1.0f;
  den.x = (agap.x > thr.x) ? (gap.x * ga.x) : (mid.x * ga.x);
  num.y = (agap.y > thr.y) ? (f_g.y - f_b.y) : 1.0f;
  den.y = (agap.y > thr.y) ? (gap.y * ga.y) : (mid.y * ga.y);
  num.z = (agap.z > thr.z) ? (f_g.z - f_b.z) : 1.0f;
  den.z = (agap.z > thr.z) ? (gap.z * ga.z) : (mid.z * ga.z);
  num.w = (agap.w > thr.w) ? (f_g.w - f_b.w) : 1.0f;
  den.w = (agap.w > thr.w) ? (gap.w * ga.w) : (mid.w * ga.w);
  const f4 cg = num * v_rcp(den);
  const f4 wd = (f_a - f_b) * inv_den_a;

  // logm = c2*A^2 + c1*A + c0*I   (collapse of f_b*I + wd*Pnum + cg*N)
  const f4 sbg = beta + gamma, pbg = beta * gamma;
  const f4 sab = alpha + beta, pab = alpha * beta;
  const f4 c2 = wd + cg;
  const f4 c1 = -(wd * sbg + cg * sab);
  const f4 c0 = f_b + wd * pbg + cg * pab;

  const f4 L0 = c2 * s00 + c1 * a00 + c0;
  const f4 L1 = c2 * s01 + c1 * a01;
  const f4 L2 = c2 * s02 + c1 * a02;
  const f4 L3 = c2 * s11 + c1 * a11 + c0;
  const f4 L4 = c2 * s12 + c1 * a12;
  const f4 L5 = c2 * s22 + c1 * a22 + c0;

  // pair A in lanes {x,y}, pair B in lanes {z,w}
  const float dA0 = L0.x - L0.y, dB0 = L0.z - L0.w;
  const float dA1 = L1.x - L1.y, dB1 = L1.z - L1.w;
  const float dA2 = L2.x - L2.y, dB2 = L2.z - L2.w;
  const float dA3 = L3.x - L3.y, dB3 = L3.z - L3.w;
  const float dA4 = L4.x - L4.y, dB4 = L4.z - L4.w;
  const float dA5 = L5.x - L5.y, dB5 = L5.z - L5.w;
  f2 out;
  out.x = dA0 * dA0 + dA3 * dA3 + dA5 * dA5 + 2.0f * (dA1 * dA1 + dA2 * dA2 + dA4 * dA4);
  out.y = dB0 * dB0 + dB3 * dB3 + dB5 * dB5 + 2.0f * (dB1 * dB1 + dB2 * dB2 + dB4 * dB4);
  return out;
}

// Each work-item = 2 consecutive matrix pairs (18 floats per tensor = 8 used
// float2 loads per tensor; float2 idx 3 holds only unused lower-tri entries).
__global__ void __launch_bounds__(256, 4)
leloss_partial(const float* __restrict__ d1, const float* __restrict__ d2,
               float* __restrict__ partial, int nmat) {
  const int nitems = (nmat + 1) >> 1;
  const int stride = gridDim.x * blockDim.x;
  const int tid = threadIdx.x;
  float acc = 0.0f;

  for (int i = blockIdx.x * blockDim.x + tid; i < nitems; i += stride) {
    f4 m00, m01, m02, m11, m12, m22;
    const bool haveB = (2 * i + 1 < nmat);
    if (haveB) {
      const float2* gA = reinterpret_cast<const float2*>(d1) + (size_t)i * 9;
      const float2* gB = reinterpret_cast<const float2*>(d2) + (size_t)i * 9;
      const float2 r0 = gA[0], r1 = gA[1], r2 = gA[2], r4 = gA[4],
                   r5 = gA[5], r6 = gA[6], r7 = gA[7], r8 = gA[8];
      const float2 q0 = gB[0], q1 = gB[1], q2 = gB[2], q4 = gB[4],
                   q5 = gB[5], q6 = gB[6], q7 = gB[7], q8 = gB[8];
      m00 = f4{r0.x, q0.x, r4.y, q4.y};
      m01 = f4{r0.y, q0.y, r5.x, q5.x};
      m02 = f4{r1.x, q1.x, r5.y, q5.y};
      m11 = f4{r2.x, q2.x, r6.y, q6.y};
      m12 = f4{r2.y, q2.y, r7.x, q7.x};
      m22 = f4{r4.x, q4.x, r8.y, q8.y};
    } else {
      // odd tail: single matrix pair, duplicated into B lanes (B loss masked)
      const size_t base = (size_t)(2 * i) * 9;
      m00 = f4{d1[base + 0], d2[base + 0], d1[base + 0], d2[base + 0]};
      m01 = f4{d1[base + 1], d2[base + 1], d1[base + 1], d2[base + 1]};
      m02 = f4{d1[base + 2], d2[base + 2], d1[base + 2], d2[base + 2]};
      m11 = f4{d1[base + 4], d2[base + 4], d1[base + 4], d2[base + 4]};
      m12 = f4{d1[base + 5], d2[base + 5], d1[base + 5], d2[base + 5]};
      m22 = f4{d1[base + 8], d2[base + 8], d1[base + 8], d2[base + 8]};
    }
    const f2 l = pair_loss(m00, m01, m02, m11, m12, m22);
    acc += l.x + (haveB ? l.y : 0.0f);
  }

  // wave reduce (64 lanes)
#pragma unroll
  for (int off = 32; off > 0; off >>= 1) acc += __shfl_down(acc, off, 64);

  __shared__ float wsum[4];
  const int lane = tid & 63;
  const int wid  = tid >> 6;
  if (lane == 0) wsum[wid] = acc;
  __syncthreads();
  if (tid == 0) {
    partial[blockIdx.x] = wsum[0] + wsum[1] + wsum[2] + wsum[3];
  }
}

__global__ void __launch_bounds__(256)
leloss_reduce(const float* __restrict__ partial, int n,
              float* __restrict__ out, double inv_count) {
  double s = 0.0;
  for (int i = threadIdx.x; i < n; i += 256) s += (double)partial[i];
#pragma unroll
  for (int off = 32; off > 0; off >>= 1) s += __shfl_down(s, off, 64);

  __shared__ double wsum[4];
  const int lane = threadIdx.x & 63;
  const int wid  = threadIdx.x >> 6;
  if (lane == 0) wsum[wid] = s;
  __syncthreads();
  if (threadIdx.x == 0) {
    const double total = wsum[0] + wsum[1] + wsum[2] + wsum[3];
    out[0] = (float)(total * inv_count);
  }
}

extern "C" void kernel_launch(void* const* d_in, const int* in_sizes, int n_in,
                              void* d_out, int out_size, void* d_ws, size_t ws_size,
                              hipStream_t stream) {
  const float* d1 = (const float*)d_in[0];
  const float* d2 = (const float*)d_in[1];
  float* out = (float*)d_out;
  float* partial = (float*)d_ws;

  const long long nelem = (long long)in_sizes[0];
  const int nmat   = (int)(nelem / 9);
  const int nitems = (nmat + 1) >> 1;
  int nblocks = (nitems + 255) / 256;
  if (nblocks > 2048) nblocks = 2048;

  leloss_partial<<<nblocks, 256, 0, stream>>>(d1, d2, partial, nmat);

  const double inv_count = 1.0 / ((double)nmat * 9.0);
  leloss_reduce<<<1, 256, 0, stream>>>(partial, nblocks, out, inv_count);
}